// Round 3
// baseline (462.254 us; speedup 1.0000x reference)
//
#include <hip/hip_runtime.h>
#include <stdint.h>

#define N 8192
#define FD 64
#define NC 10
#define SK 8
#define BM 64
#define BK 64

typedef __attribute__((ext_vector_type(8))) __bf16 bf16x8;
typedef __attribute__((ext_vector_type(4))) float f32x4;
typedef __attribute__((ext_vector_type(4))) float vf4;   // native vector for nontemporal builtin

__device__ __forceinline__ unsigned short f2bf(float f) {
    unsigned u = __builtin_bit_cast(unsigned, f);
    u += 0x7fffu + ((u >> 16) & 1u);   // round-to-nearest-even
    return (unsigned short)(u >> 16);
}

// async global->LDS, 16B per lane. LDS dest must be wave-uniform base + lane*16.
__device__ __forceinline__ void g2l16(const void* g, void* l) {
    __builtin_amdgcn_global_load_lds(
        (const __attribute__((address_space(1))) unsigned int*)g,
        (__attribute__((address_space(3))) unsigned int*)l, 16, 0, 0);
}

// ---------------------------------------------------------------------------
// Kernel 1 (FUSED): row-sum of fp32 A + cast A->bf16 + d = rsqrt(sum) +
// layer-1  yT[f][r] = bf16( d[r] * (emb @ W1)[r][f] ).
// Legal because row r's d depends only on row r's sum, and this block's xw
// phase touches only its own 32 rows. 256 blocks x 512 threads:
//  - W1 (16 KB) + emb rows (8 KB) staged FIRST -> their latency hides under
//    the 1 MB/block A stream.
//  - A phase: wave w owns rows 4w..4w+3, 16 lanes/row, NT vf4 loads
//    (A is dead after; keeps Abf L3-resident for the two spmm passes),
//    bf16 cast stored inline. 16-lane shfl_xor reduce -> d in LDS.
//  - xw phase: identical math to the old xw_inner512, d read from LDS.
// Removes one dispatch boundary vs the split version.
// ---------------------------------------------------------------------------
__global__ __launch_bounds__(512) void rowsum_xw(const float* __restrict__ A,
                                                 const float* __restrict__ emb,
                                                 const float* __restrict__ W,
                                                 unsigned short* __restrict__ Abf,
                                                 float* __restrict__ dvec,
                                                 unsigned short* __restrict__ yT) {
    __shared__ float Xs[32][69];
    __shared__ __align__(16) float Ws[64 * 64];
    __shared__ float dsh[32];
    const int t = threadIdx.x;
    const int r0 = blockIdx.x * 32;

    // stage W1 + emb (issued first; completes under the A stream)
    const float4* W4 = (const float4*)W;
#pragma unroll
    for (int p = 0; p < 2; p++) ((float4*)Ws)[p * 512 + t] = W4[p * 512 + t];
    {
        float4 v = ((const float4*)emb + (size_t)r0 * 16)[t];   // 512 = 32 rows x 16
        int row = t >> 4, f4 = (t & 15) * 4;
        Xs[row][f4] = v.x; Xs[row][f4 + 1] = v.y; Xs[row][f4 + 2] = v.z; Xs[row][f4 + 3] = v.w;
    }

    // A phase: rowsum + cast. wave w -> rows 4w..4w+3; 16 lanes per row.
    const int l = t & 63, w = t >> 6;
    const int lr = l & 15;
    const int rloc = w * 4 + (l >> 4);
    const int rg = r0 + rloc;
    const vf4* Arow = (const vf4*)(A + (size_t)rg * N);
    ushort4* Brow = (ushort4*)(Abf + (size_t)rg * N);
    float s = 0.f;
#pragma unroll 8
    for (int i = 0; i < 128; i++) {
        int c4 = lr + 16 * i;                   // 16 lanes -> 256 B contiguous
        vf4 v = __builtin_nontemporal_load(Arow + c4);
        s += (v.x + v.y) + (v.z + v.w);
        ushort4 o;
        o.x = f2bf(v.x); o.y = f2bf(v.y); o.z = f2bf(v.z); o.w = f2bf(v.w);
        Brow[c4] = o;                           // regular store: keep Abf L3-resident
    }
#pragma unroll
    for (int m = 8; m > 0; m >>= 1) s += __shfl_xor(s, m, 64);  // 16-lane group sum
    if (lr == 0) {
        float d = s > 0.f ? rsqrtf(s) : 0.f;
        dsh[rloc] = d;
        dvec[rg] = d;                           // combine kernels still read global dvec
    }
    __syncthreads();

    // xw phase: wave w + lane-half fh own f in [w*8+fh*4, +4); lane owns row l&31.
    const int row = l & 31, fh = l >> 5;
    const int fbase = w * 8 + fh * 4;
    float acc0 = 0.f, acc1 = 0.f, acc2 = 0.f, acc3 = 0.f;
#pragma unroll 8
    for (int j = 0; j < 64; j++) {
        float xv = Xs[row][j];
        float4 wv = *(const float4*)(Ws + j * 64 + fbase);
        acc0 += xv * wv.x; acc1 += xv * wv.y; acc2 += xv * wv.z; acc3 += xv * wv.w;
    }
    float dl = dsh[row];
    yT[(size_t)(fbase + 0) * N + r0 + row] = f2bf(dl * acc0);
    yT[(size_t)(fbase + 1) * N + r0 + row] = f2bf(dl * acc1);
    yT[(size_t)(fbase + 2) * N + r0 + row] = f2bf(dl * acc2);
    yT[(size_t)(fbase + 3) * N + r0 + row] = f2bf(dl * acc3);
}

// ---------------------------------------------------------------------------
// Shared inner (512 threads, 32 rows/block) for the combine kernels.
// ---------------------------------------------------------------------------
__device__ __forceinline__ void xw_inner512(const float (*Xs)[69], const float* Ws,
                                            const float* __restrict__ dvec,
                                            unsigned short* __restrict__ yT,
                                            int r0, int t) {
    const int l = t & 63, w = t >> 6;
    const int row = l & 31, fh = l >> 5;
    const int fbase = w * 8 + fh * 4;
    float acc0 = 0.f, acc1 = 0.f, acc2 = 0.f, acc3 = 0.f;
#pragma unroll 8
    for (int j = 0; j < 64; j++) {
        float xv = Xs[row][j];
        float4 wv = *(const float4*)(Ws + j * 64 + fbase);
        acc0 += xv * wv.x; acc1 += xv * wv.y; acc2 += xv * wv.z; acc3 += xv * wv.w;
    }
    float dl = dvec[r0 + row];
    yT[(size_t)(fbase + 0) * N + r0 + row] = f2bf(dl * acc0);
    yT[(size_t)(fbase + 1) * N + r0 + row] = f2bf(dl * acc1);
    yT[(size_t)(fbase + 2) * N + r0 + row] = f2bf(dl * acc2);
    yT[(size_t)(fbase + 3) * N + r0 + row] = f2bf(dl * acc3);
}

// ---------------------------------------------------------------------------
// Kernel 2: split-K bf16 MFMA GEMM, BM=64, BK=64, SK=8, depth-2 pipeline with
// COUNTED vmcnt (unchanged from round 2 -- attribution control).
// ---------------------------------------------------------------------------
__global__ __launch_bounds__(256) void spmm(const unsigned short* __restrict__ Abf,
                                            const unsigned short* __restrict__ yT,
                                            float* __restrict__ partial) {
    constexpr int KS = N / SK;               // 1024
    constexpr int NTILE = KS / BK;           // 16
    __shared__ __align__(16) unsigned short As[2][BM * BK];  // 2 x 8 KB
    __shared__ __align__(16) unsigned short Ys[2][64 * BK];  // 2 x 8 KB
    const int t = threadIdx.x;
    const int m0 = blockIdx.x * BM;
    const int kbase = blockIdx.y * KS;
    const int lane = t & 63, w = t >> 6;
    const int quad = lane >> 4, lr = lane & 15;

    f32x4 acc[4];
#pragma unroll
    for (int nt = 0; nt < 4; nt++) {
        acc[nt].x = 0.f; acc[nt].y = 0.f; acc[nt].z = 0.f; acc[nt].w = 0.f;
    }

    auto stage = [&](int buf, int k0) {
#pragma unroll
        for (int p = 0; p < 2; p++) {          // As: 512 slots of 16B
            int s = p * 256 + t;
            int row = s >> 3, c = (s & 7) ^ (row & 7);
            g2l16(Abf + (size_t)(m0 + row) * N + k0 + c * 8, &As[buf][s * 8]);
        }
#pragma unroll
        for (int p = 0; p < 2; p++) {          // Ys: 512 slots of 16B
            int s = p * 256 + t;
            int row = s >> 3, c = (s & 7) ^ (row & 7);
            g2l16(yT + (size_t)row * N + k0 + c * 8, &Ys[buf][s * 8]);
        }
    };

    stage(0, kbase);                           // out: 4
    stage(1, kbase + BK);                      // out: 8

    for (int ti = 0; ti < NTILE; ++ti) {
        const int cur = ti & 1;
        if (ti < NTILE - 1) {
            asm volatile("s_waitcnt vmcnt(4)" ::: "memory");
        } else {
            asm volatile("s_waitcnt vmcnt(0)" ::: "memory");
        }
        asm volatile("s_barrier" ::: "memory");   // publish buf[cur]
#pragma unroll
        for (int kk = 0; kk < 2; kk++) {
            int cc = kk * 4 + quad;            // global chunk 0..7
            int cs = cc ^ (lr & 7);            // swizzled LDS chunk slot
            bf16x8 af = *(const bf16x8*)(&As[cur][((w * 16 + lr) * 8 + cs) * 8]);
#pragma unroll
            for (int nt = 0; nt < 4; nt++) {
                bf16x8 bv = *(const bf16x8*)(&Ys[cur][((nt * 16 + lr) * 8 + cs) * 8]);
                acc[nt] = __builtin_amdgcn_mfma_f32_16x16x32_bf16(af, bv, acc[nt], 0, 0, 0);
            }
        }
        if (ti + 2 < NTILE) {
            asm volatile("s_barrier" ::: "memory");   // all waves done with buf[cur]
            stage(cur, kbase + (ti + 2) * BK);
        }
    }
    // C/D: row = quad*4 + r, col = lr
#pragma unroll
    for (int nt = 0; nt < 4; nt++)
#pragma unroll
        for (int r = 0; r < 4; r++) {
            int m = m0 + w * 16 + quad * 4 + r;
            partial[((size_t)blockIdx.y * N + m) * FD + nt * 16 + lr] = acc[nt][r];
        }
}

// ---------------------------------------------------------------------------
// Kernel 3: fused split-K combine + relu + d-scale + (x @ W2) -> yT (layer 2)
// ---------------------------------------------------------------------------
__global__ __launch_bounds__(512) void combine_xw(const float* __restrict__ partial,
                                                  const float* __restrict__ W,
                                                  const float* __restrict__ dvec,
                                                  unsigned short* __restrict__ yT) {
    __shared__ float Xs[32][69];
    __shared__ __align__(16) float Ws[64 * 64];
    const int t = threadIdx.x;
    const int r0 = blockIdx.x * 32;
    const float4* W4 = (const float4*)W;
    const vf4* p4 = (const vf4*)partial;
#pragma unroll
    for (int p = 0; p < 2; p++) ((float4*)Ws)[p * 512 + t] = W4[p * 512 + t];
    {
        int row = t >> 4, f4c = t & 15;        // 512 slots = 32 rows x 16
        size_t base = (size_t)(r0 + row) * 16 + f4c;
        vf4 s = __builtin_nontemporal_load(p4 + base);
#pragma unroll
        for (int sk = 1; sk < SK; sk++)
            s += __builtin_nontemporal_load(p4 + (size_t)sk * (N * 16) + base);
        float dm = dvec[r0 + row];
        int f4 = f4c * 4;
        Xs[row][f4]     = fmaxf(0.f, dm * s.x);
        Xs[row][f4 + 1] = fmaxf(0.f, dm * s.y);
        Xs[row][f4 + 2] = fmaxf(0.f, dm * s.z);
        Xs[row][f4 + 3] = fmaxf(0.f, dm * s.w);
    }
    __syncthreads();
    xw_inner512(Xs, Ws, dvec, yT, r0, t);
}

// ---------------------------------------------------------------------------
// Kernel 4: fused split-K combine + relu + d-scale + classifier (x @ Wc + bc)
// ---------------------------------------------------------------------------
__global__ __launch_bounds__(512) void combine_logits(const float* __restrict__ partial,
                                                      const float* __restrict__ dvec,
                                                      const float* __restrict__ Wc,
                                                      const float* __restrict__ bc,
                                                      float* __restrict__ out) {
    __shared__ float Xs[32][69];
    __shared__ float Wcs[64][10];
    __shared__ float bcs[10];
    const int t = threadIdx.x;
    const int r0 = blockIdx.x * 32;
    const vf4* p4 = (const vf4*)partial;
    {
        int row = t >> 4, f4c = t & 15;
        size_t base = (size_t)(r0 + row) * 16 + f4c;
        vf4 s = __builtin_nontemporal_load(p4 + base);
#pragma unroll
        for (int sk = 1; sk < SK; sk++)
            s += __builtin_nontemporal_load(p4 + (size_t)sk * (N * 16) + base);
        float dm = dvec[r0 + row];
        int f4 = f4c * 4;
        Xs[row][f4]     = fmaxf(0.f, dm * s.x);
        Xs[row][f4 + 1] = fmaxf(0.f, dm * s.y);
        Xs[row][f4 + 2] = fmaxf(0.f, dm * s.z);
        Xs[row][f4 + 3] = fmaxf(0.f, dm * s.w);
    }
    for (int i = t; i < 640; i += 512) Wcs[i / 10][i % 10] = Wc[i];
    if (t < 10) bcs[t] = bc[t];
    __syncthreads();
    if (t < 320) {
        int r = t / 10, c = t - r * 10;
        float a = bcs[c];
#pragma unroll
        for (int j = 0; j < 64; j++) a += Xs[r][j] * Wcs[j][c];
        out[(size_t)(r0 + r) * NC + c] = a;
    }
}

// ---------------------------------------------------------------------------
extern "C" void kernel_launch(void* const* d_in, const int* in_sizes, int n_in,
                              void* d_out, int out_size, void* d_ws, size_t ws_size,
                              hipStream_t stream) {
    const float* A   = (const float*)d_in[0];
    const float* emb = (const float*)d_in[1];
    const float* W1  = (const float*)d_in[2];
    const float* W2  = (const float*)d_in[3];
    const float* Wc  = (const float*)d_in[4];
    const float* bc  = (const float*)d_in[5];
    char* ws = (char*)d_ws;

    unsigned short* Abf  = (unsigned short*)(ws);                 // 134,217,728 B
    float* dvec          = (float*)(ws + 134217728);              //      32,768 B
    unsigned short* yT   = (unsigned short*)(ws + 134250496);     //   1,048,576 B
    float* partial       = (float*)(ws + 135299072);              //  16,777,216 B (SK=8)
    float* out           = (float*)d_out;

    // layer 1 (rowsum/cast fused with xw)
    rowsum_xw<<<N / 32, 512, 0, stream>>>(A, emb, W1, Abf, dvec, yT);
    spmm<<<dim3(N / BM, SK), 256, 0, stream>>>(Abf, yT, partial);

    // layer 2 (combine fused with xw)
    combine_xw<<<N / 32, 512, 0, stream>>>(partial, W2, dvec, yT);
    spmm<<<dim3(N / BM, SK), 256, 0, stream>>>(Abf, yT, partial);

    // epilogue (combine fused with classifier)
    combine_logits<<<N / 32, 512, 0, stream>>>(partial, dvec, Wc, bc, out);
}

// Round 4
// 419.090 us; speedup vs baseline: 1.1030x; 1.1030x over previous
//
#include <hip/hip_runtime.h>
#include <stdint.h>

#define N 8192
#define FD 64
#define NC 10
#define SK 8
#define BM 64
#define BK 64

typedef __attribute__((ext_vector_type(8))) __bf16 bf16x8;
typedef __attribute__((ext_vector_type(4))) float f32x4;
typedef __attribute__((ext_vector_type(4))) float vf4;   // native vector for nontemporal builtin

__device__ __forceinline__ unsigned short f2bf(float f) {
    unsigned u = __builtin_bit_cast(unsigned, f);
    u += 0x7fffu + ((u >> 16) & 1u);   // round-to-nearest-even
    return (unsigned short)(u >> 16);
}

// async global->LDS, 16B per lane. LDS dest must be wave-uniform base + lane*16.
__device__ __forceinline__ void g2l16(const void* g, void* l) {
    __builtin_amdgcn_global_load_lds(
        (const __attribute__((address_space(1))) unsigned int*)g,
        (__attribute__((address_space(3))) unsigned int*)l, 16, 0, 0);
}

// ---------------------------------------------------------------------------
// Kernel 1: fused row-sum of fp32 A + cast A -> bf16 (RNE). One block per row.
// 8192 blocks: block-level parallelism is the latency-hiding resource for this
// pure memory pump (round-3 fusion to 256 blocks cost +42 us -- do not refuse).
// NT loads for the fp32 stream (dead after this kernel) keep Abf L3-resident.
// At its 402-MB roofline (~64 us).
// ---------------------------------------------------------------------------
__global__ __launch_bounds__(256) void rowsum_cast(const float* __restrict__ A,
                                                   unsigned short* __restrict__ Abf,
                                                   float* __restrict__ dvec) {
    const int row = blockIdx.x;
    const int t = threadIdx.x;
    const vf4* Arow = (const vf4*)(A + (size_t)row * N);
    ushort4* Brow = (ushort4*)(Abf + (size_t)row * N);
    float s = 0.f;
#pragma unroll
    for (int i = 0; i < 8; i++) {
        int c4 = t + 256 * i;
        vf4 v = __builtin_nontemporal_load(Arow + c4);
        s += (v.x + v.y) + (v.z + v.w);
        ushort4 o;
        o.x = f2bf(v.x); o.y = f2bf(v.y); o.z = f2bf(v.z); o.w = f2bf(v.w);
        Brow[c4] = o;   // regular store: keep Abf L3-resident
    }
#pragma unroll
    for (int off = 32; off > 0; off >>= 1) s += __shfl_down(s, off, 64);
    __shared__ float red[4];
    if ((t & 63) == 0) red[t >> 6] = s;
    __syncthreads();
    if (t == 0) {
        float tot = (red[0] + red[1]) + (red[2] + red[3]);
        dvec[row] = tot > 0.f ? rsqrtf(tot) : 0.f;
    }
}

// ---------------------------------------------------------------------------
// Shared inner (512 threads, 32 rows/block): wave w (0..7) + lane-half fh own
// f in [w*8+fh*4, +4). Lane l owns row l&31 (2 lanes/row broadcast, free).
// ---------------------------------------------------------------------------
__device__ __forceinline__ void xw_inner512(const float (*Xs)[69], const float* Ws,
                                            const float* __restrict__ dvec,
                                            unsigned short* __restrict__ yT,
                                            int r0, int t) {
    const int l = t & 63, w = t >> 6;
    const int row = l & 31, fh = l >> 5;
    const int fbase = w * 8 + fh * 4;
    float acc0 = 0.f, acc1 = 0.f, acc2 = 0.f, acc3 = 0.f;
#pragma unroll 8
    for (int j = 0; j < 64; j++) {
        float xv = Xs[row][j];
        float4 wv = *(const float4*)(Ws + j * 64 + fbase);
        acc0 += xv * wv.x; acc1 += xv * wv.y; acc2 += xv * wv.z; acc3 += xv * wv.w;
    }
    float dl = dvec[r0 + row];
    yT[(size_t)(fbase + 0) * N + r0 + row] = f2bf(dl * acc0);
    yT[(size_t)(fbase + 1) * N + r0 + row] = f2bf(dl * acc1);
    yT[(size_t)(fbase + 2) * N + r0 + row] = f2bf(dl * acc2);
    yT[(size_t)(fbase + 3) * N + r0 + row] = f2bf(dl * acc3);
}

// ---------------------------------------------------------------------------
// Kernel 2 (layer 1): yT[f][r] = bf16( d[r] * (x @ W)[r][f] ), x from global.
// ---------------------------------------------------------------------------
__global__ __launch_bounds__(512) void xw_from_global(const float* __restrict__ x,
                                                      const float* __restrict__ W,
                                                      const float* __restrict__ dvec,
                                                      unsigned short* __restrict__ yT) {
    __shared__ float Xs[32][69];
    __shared__ __align__(16) float Ws[64 * 64];
    const int t = threadIdx.x;
    const int r0 = blockIdx.x * 32;
    const float4* x4 = (const float4*)x + (size_t)r0 * 16;
    const float4* W4 = (const float4*)W;
#pragma unroll
    for (int p = 0; p < 2; p++) ((float4*)Ws)[p * 512 + t] = W4[p * 512 + t];
    {
        float4 v = x4[t];                       // 512 float4 = 32 rows x 16
        int row = t >> 4, f4 = (t & 15) * 4;
        Xs[row][f4] = v.x; Xs[row][f4 + 1] = v.y; Xs[row][f4 + 2] = v.z; Xs[row][f4 + 3] = v.w;
    }
    __syncthreads();
    xw_inner512(Xs, Ws, dvec, yT, r0, t);
}

// ---------------------------------------------------------------------------
// Kernel 3: split-K bf16 MFMA GEMM, BM=64, BK=64, SK=8, depth-2 pipeline with
// COUNTED vmcnt (T4): per tile  s_waitcnt vmcnt(4) -> s_barrier -> MFMA ->
// s_barrier -> stage(ti+2).  No vmcnt(0) drain in the main loop.
// 1024 blocks = exactly 4/CU at 32 KB LDS: perfect co-residency, no tail.
// (Depth-3 rejected: 48 KB LDS -> 3 blocks/CU -> 256-block straggler tail.)
// XOR swizzle on the GLOBAL address (LDS dest lane-contiguous).
// ---------------------------------------------------------------------------
__global__ __launch_bounds__(256) void spmm(const unsigned short* __restrict__ Abf,
                                            const unsigned short* __restrict__ yT,
                                            float* __restrict__ partial) {
    constexpr int KS = N / SK;               // 1024
    constexpr int NTILE = KS / BK;           // 16
    __shared__ __align__(16) unsigned short As[2][BM * BK];  // 2 x 8 KB
    __shared__ __align__(16) unsigned short Ys[2][64 * BK];  // 2 x 8 KB
    const int t = threadIdx.x;
    const int m0 = blockIdx.x * BM;
    const int kbase = blockIdx.y * KS;
    const int lane = t & 63, w = t >> 6;
    const int quad = lane >> 4, lr = lane & 15;

    f32x4 acc[4];
#pragma unroll
    for (int nt = 0; nt < 4; nt++) {
        acc[nt].x = 0.f; acc[nt].y = 0.f; acc[nt].z = 0.f; acc[nt].w = 0.f;
    }

    auto stage = [&](int buf, int k0) {
#pragma unroll
        for (int p = 0; p < 2; p++) {          // As: 512 slots of 16B
            int s = p * 256 + t;
            int row = s >> 3, c = (s & 7) ^ (row & 7);
            g2l16(Abf + (size_t)(m0 + row) * N + k0 + c * 8, &As[buf][s * 8]);
        }
#pragma unroll
        for (int p = 0; p < 2; p++) {          // Ys: 512 slots of 16B
            int s = p * 256 + t;
            int row = s >> 3, c = (s & 7) ^ (row & 7);
            g2l16(yT + (size_t)row * N + k0 + c * 8, &Ys[buf][s * 8]);
        }
    };

    stage(0, kbase);                           // out: 4
    stage(1, kbase + BK);                      // out: 8

    for (int ti = 0; ti < NTILE; ++ti) {
        const int cur = ti & 1;
        if (ti < NTILE - 1) {
            asm volatile("s_waitcnt vmcnt(4)" ::: "memory");
        } else {
            asm volatile("s_waitcnt vmcnt(0)" ::: "memory");
        }
        asm volatile("s_barrier" ::: "memory");   // publish buf[cur]
#pragma unroll
        for (int kk = 0; kk < 2; kk++) {
            int cc = kk * 4 + quad;            // global chunk 0..7
            int cs = cc ^ (lr & 7);            // swizzled LDS chunk slot
            bf16x8 af = *(const bf16x8*)(&As[cur][((w * 16 + lr) * 8 + cs) * 8]);
#pragma unroll
            for (int nt = 0; nt < 4; nt++) {
                bf16x8 bv = *(const bf16x8*)(&Ys[cur][((nt * 16 + lr) * 8 + cs) * 8]);
                acc[nt] = __builtin_amdgcn_mfma_f32_16x16x32_bf16(af, bv, acc[nt], 0, 0, 0);
            }
        }
        if (ti + 2 < NTILE) {
            asm volatile("s_barrier" ::: "memory");   // all waves done with buf[cur]
            stage(cur, kbase + (ti + 2) * BK);
        }
    }
    // C/D: row = quad*4 + r, col = lr
#pragma unroll
    for (int nt = 0; nt < 4; nt++)
#pragma unroll
        for (int r = 0; r < 4; r++) {
            int m = m0 + w * 16 + quad * 4 + r;
            partial[((size_t)blockIdx.y * N + m) * FD + nt * 16 + lr] = acc[nt][r];
        }
}

// ---------------------------------------------------------------------------
// Kernel 4: fused split-K combine + relu + d-scale + (x @ W2) -> yT (layer 2)
// NT loads on partial (dead after read; protects Abf L3 residency for spmm2).
// ---------------------------------------------------------------------------
__global__ __launch_bounds__(512) void combine_xw(const float* __restrict__ partial,
                                                  const float* __restrict__ W,
                                                  const float* __restrict__ dvec,
                                                  unsigned short* __restrict__ yT) {
    __shared__ float Xs[32][69];
    __shared__ __align__(16) float Ws[64 * 64];
    const int t = threadIdx.x;
    const int r0 = blockIdx.x * 32;
    const float4* W4 = (const float4*)W;
    const vf4* p4 = (const vf4*)partial;
#pragma unroll
    for (int p = 0; p < 2; p++) ((float4*)Ws)[p * 512 + t] = W4[p * 512 + t];
    {
        int row = t >> 4, f4c = t & 15;        // 512 slots = 32 rows x 16
        size_t base = (size_t)(r0 + row) * 16 + f4c;
        vf4 s = __builtin_nontemporal_load(p4 + base);
#pragma unroll
        for (int sk = 1; sk < SK; sk++)
            s += __builtin_nontemporal_load(p4 + (size_t)sk * (N * 16) + base);
        float dm = dvec[r0 + row];
        int f4 = f4c * 4;
        Xs[row][f4]     = fmaxf(0.f, dm * s.x);
        Xs[row][f4 + 1] = fmaxf(0.f, dm * s.y);
        Xs[row][f4 + 2] = fmaxf(0.f, dm * s.z);
        Xs[row][f4 + 3] = fmaxf(0.f, dm * s.w);
    }
    __syncthreads();
    xw_inner512(Xs, Ws, dvec, yT, r0, t);
}

// ---------------------------------------------------------------------------
// Kernel 5: fused split-K combine + relu + d-scale + classifier (x @ Wc + bc)
// ---------------------------------------------------------------------------
__global__ __launch_bounds__(512) void combine_logits(const float* __restrict__ partial,
                                                      const float* __restrict__ dvec,
                                                      const float* __restrict__ Wc,
                                                      const float* __restrict__ bc,
                                                      float* __restrict__ out) {
    __shared__ float Xs[32][69];
    __shared__ float Wcs[64][10];
    __shared__ float bcs[10];
    const int t = threadIdx.x;
    const int r0 = blockIdx.x * 32;
    const vf4* p4 = (const vf4*)partial;
    {
        int row = t >> 4, f4c = t & 15;
        size_t base = (size_t)(r0 + row) * 16 + f4c;
        vf4 s = __builtin_nontemporal_load(p4 + base);
#pragma unroll
        for (int sk = 1; sk < SK; sk++)
            s += __builtin_nontemporal_load(p4 + (size_t)sk * (N * 16) + base);
        float dm = dvec[r0 + row];
        int f4 = f4c * 4;
        Xs[row][f4]     = fmaxf(0.f, dm * s.x);
        Xs[row][f4 + 1] = fmaxf(0.f, dm * s.y);
        Xs[row][f4 + 2] = fmaxf(0.f, dm * s.z);
        Xs[row][f4 + 3] = fmaxf(0.f, dm * s.w);
    }
    for (int i = t; i < 640; i += 512) Wcs[i / 10][i % 10] = Wc[i];
    if (t < 10) bcs[t] = bc[t];
    __syncthreads();
    if (t < 320) {
        int r = t / 10, c = t - r * 10;
        float a = bcs[c];
#pragma unroll
        for (int j = 0; j < 64; j++) a += Xs[r][j] * Wcs[j][c];
        out[(size_t)(r0 + r) * NC + c] = a;
    }
}

// ---------------------------------------------------------------------------
extern "C" void kernel_launch(void* const* d_in, const int* in_sizes, int n_in,
                              void* d_out, int out_size, void* d_ws, size_t ws_size,
                              hipStream_t stream) {
    const float* A   = (const float*)d_in[0];
    const float* emb = (const float*)d_in[1];
    const float* W1  = (const float*)d_in[2];
    const float* W2  = (const float*)d_in[3];
    const float* Wc  = (const float*)d_in[4];
    const float* bc  = (const float*)d_in[5];
    char* ws = (char*)d_ws;

    unsigned short* Abf  = (unsigned short*)(ws);                 // 134,217,728 B
    float* dvec          = (float*)(ws + 134217728);              //      32,768 B
    unsigned short* yT   = (unsigned short*)(ws + 134250496);     //   1,048,576 B
    float* partial       = (float*)(ws + 135299072);              //  16,777,216 B (SK=8)
    float* out           = (float*)d_out;

    rowsum_cast<<<N, 256, 0, stream>>>(A, Abf, dvec);

    // layer 1
    xw_from_global<<<N / 32, 512, 0, stream>>>(emb, W1, dvec, yT);
    spmm<<<dim3(N / BM, SK), 256, 0, stream>>>(Abf, yT, partial);

    // layer 2 (combine fused with xw)
    combine_xw<<<N / 32, 512, 0, stream>>>(partial, W2, dvec, yT);
    spmm<<<dim3(N / BM, SK), 256, 0, stream>>>(Abf, yT, partial);

    // epilogue (combine fused with classifier)
    combine_logits<<<N / 32, 512, 0, stream>>>(partial, dvec, Wc, bc, out);
}